// Round 10
// baseline (221.545 us; speedup 1.0000x reference)
//
#include <hip/hip_runtime.h>
#include <math.h>

#define NB 16      // batch
#define NN 4096    // nodes
#define NE 65536   // edges
#define DD 256     // feature dim
#define NR 4       // relations (excl. self)
#define VG 30000
#define VS 20000
#define NTG 118    // ceil(7500/64): logits tiles (64 float4 = 256 v per block)
#define NTS 79     // ceil(5000/64)
#define FTG 30     // ceil(VG/1024) final tiles
#define FTS 20     // ceil(VS/1024)
#define NCHK 16    // edge-scan chunks per graph
#define CCAP 16    // match capacity per (graph, chunk); matches/chunk ~ Poisson(1)

// ws layout (float/int offsets):
#define WS_MCNT 0      // mcnt [NB][NCHK] int              (256)
#define WS_MAT  256    // matches [NB][NCHK][CCAP] int     (4096)
#define WS_H0P  4352   // h0p [NR+1][DD][NB] float         (20480)  per-relation partials
#define WS_PM   24832  // per-tile max partials            (3152)
#define WS_PS   27984  // per-tile sumexp partials         (3152)
// total 31136 floats ~= 125 KB. NO pre-zeroing needed anywhere.

__device__ __forceinline__ void stage16(const float* g, float* l) {
  // async global->LDS DMA, 16B per lane; LDS dest = wave-uniform base + lane*16,
  // global src is per-lane. Counted by vmcnt (drained by __syncthreads).
  __builtin_amdgcn_global_load_lds(
      (const __attribute__((address_space(1))) void*)g,
      (__attribute__((address_space(3))) void*)l, 16, 0, 0);
}

// grid (NB, NCHK), 256 thr: block (b,ch) scans edges [ch*4096, +4096) for src==0,
// appends (rel<<12|dst) to its own list via LDS-local index. No global atomics.
__global__ __launch_bounds__(256) void k_scan(
    const int* __restrict__ ei, const int* __restrict__ etp,
    int* __restrict__ mcnt, int* __restrict__ matches) {
  const int b = blockIdx.x;
  const int ch = blockIdx.y;
  const int* src = ei + (size_t)b * 2 * NE;
  const int* dst = src + NE;
  const int* etb = etp + (size_t)b * NE;
  __shared__ int lc;
  if (threadIdx.x == 0) lc = 0;
  __syncthreads();
#pragma unroll
  for (int p = 0; p < 4; ++p) {
    const int e0 = ch * 4096 + p * 1024 + threadIdx.x * 4;
    const int4 s4 = *reinterpret_cast<const int4*>(&src[e0]);
#pragma unroll
    for (int u = 0; u < 4; ++u) {
      const int sv = (u == 0) ? s4.x : (u == 1) ? s4.y : (u == 2) ? s4.z : s4.w;
      if (sv == 0) {
        const int e = e0 + u;
        const int idx = atomicAdd(&lc, 1);   // LDS atomic
        if (idx < CCAP)
          matches[(b * NCHK + ch) * CCAP + idx] = (etb[e] << 12) | dst[e];
      }
    }
  }
  __syncthreads();
  if (threadIdx.x == 0) mcnt[b * NCHK + ch] = min(lc, CCAP);
}

// grid (NR+1, 8), 256 thr: block (r, jt) gathers u_r for all 16 graphs (lists
// staged in LDS -> x-row loads pipeline), then computes u_r @ W_all[r][:, jt*32..+32]
// and writes DISJOINT slice h0p[r][j][b] (no atomics; summed at logits staging).
__global__ __launch_bounds__(256) void k_uh0(
    const float* __restrict__ x, const float* __restrict__ W_all,
    const int* __restrict__ mcnt, const int* __restrict__ matches,
    float* __restrict__ h0p) {
  const int r = blockIdx.x;   // 0 = self, 1..NR
  const int jt = blockIdx.y;  // 0..7
  const int tid = threadIdx.x;
  __shared__ float us[NB][DD];           // 16 KB
  __shared__ float red[8][NB][32];       // 16 KB
  __shared__ int lmv[NB][NCHK][CCAP];    // 16 KB
  __shared__ int lcn[NB][NCHK];
  if (r == 0) {
    for (int b = 0; b < NB; ++b) us[b][tid] = x[((size_t)b * NN) * DD + tid];
    __syncthreads();
  } else {
    for (int i = tid; i < NB * NCHK * CCAP; i += 256)
      (&lmv[0][0][0])[i] = matches[i];
    for (int i = tid; i < NB * NCHK; i += 256)
      (&lcn[0][0])[i] = mcnt[i];
    __syncthreads();
    const int rr = r - 1;
    for (int b = 0; b < NB; ++b) {
      float s = 0.f;
      int nr = 0;
      for (int ch = 0; ch < NCHK; ++ch) {
        const int n = lcn[b][ch];
        for (int i = 0; i < n; ++i) {
          const int mv = lmv[b][ch][i];
          if ((mv >> 12) == rr) {
            ++nr;
            s += x[((size_t)b * NN + (mv & 4095)) * DD + tid];
          }
        }
      }
      us[b][tid] = s * (1.f / fmaxf((float)nr, 1.f));
    }
    __syncthreads();
  }
  // GEMM slice: output rows j = jt*32..+32 of h0p[r]
  const int jl = tid & 31;
  const int kg = tid >> 5;            // 0..7, 32 k each
  const int j = jt * 32 + jl;
  const float* W = W_all + (size_t)r * DD * DD + j;
  float acc[NB];
#pragma unroll
  for (int b = 0; b < NB; ++b) acc[b] = 0.f;
  const int kb = kg * 32;
  for (int k0 = 0; k0 < 32; k0 += 8) {
    float w[8];
#pragma unroll
    for (int q = 0; q < 8; ++q) w[q] = W[(size_t)(kb + k0 + q) * DD];
#pragma unroll
    for (int q = 0; q < 8; ++q) {
#pragma unroll
      for (int b = 0; b < NB; ++b)
        acc[b] = fmaf(us[b][kb + k0 + q], w[q], acc[b]);
    }
  }
#pragma unroll
  for (int b = 0; b < NB; ++b) red[kg][b][jl] = acc[b];
  __syncthreads();
  const int bh = tid >> 5;
#pragma unroll
  for (int half = 0; half < 2; ++half) {
    const int b = bh + half * 8;
    float s = 0.f;
#pragma unroll
    for (int g = 0; g < 8; ++g) s += red[g][b][jl];
    h0p[((size_t)r * DD + jt * 32 + jl) * NB + b] = s;   // disjoint write
  }
}

// grid NTG+NTS, 256 thr (4 waves). Block = 64 float4 columns (256 v), full K=256.
// Wave w owns graphs 4w..4w+3 (no cross-wave reduce). W streamed via
// global_load_lds DMA in 16k x 1KB chunks (16 issues in flight, zero VGPR cost).
__global__ __launch_bounds__(256) void k_logits(
    const float* __restrict__ Wg, const float* __restrict__ bg,
    const float* __restrict__ Wss, const float* __restrict__ bs,
    const float* __restrict__ h0p, float* __restrict__ out,
    float* __restrict__ pm, float* __restrict__ ps) {
  const int blk = blockIdx.x;
  int tile, V4, ntiles;
  const float *W, *bias;
  float *o, *pmh, *psh;
  if (blk < NTG) {
    tile = blk; V4 = VG / 4; W = Wg; bias = bg; o = out;
    pmh = pm; psh = ps; ntiles = NTG;
  } else {
    tile = blk - NTG; V4 = VS / 4; W = Wss; bias = bs; o = out + (size_t)NB * VG;
    pmh = pm + NB * NTG; psh = ps + NB * NTG; ntiles = NTS;
  }
  const int tid = threadIdx.x;
  const int w = tid >> 6;
  const int l = tid & 63;
  __shared__ float4 hs4[DD][4];        // relu(sum_r h0p): [k][graph-quad], 16 KB
  __shared__ float wbuf[16 * 256];     // 16 k-rows x 256 floats (64 f4), 16 KB
  // build hs = relu(sum over relations of h0p)
  {
    const float4* hp4 = reinterpret_cast<const float4*>(h0p);
    for (int i = tid; i < 1024; i += 256) {
      float4 v = hp4[i];
#pragma unroll
      for (int r = 1; r <= NR; ++r) {
        const float4 t4 = hp4[r * 1024 + i];
        v.x += t4.x; v.y += t4.y; v.z += t4.z; v.w += t4.w;
      }
      v.x = fmaxf(v.x, 0.f); v.y = fmaxf(v.y, 0.f);
      v.z = fmaxf(v.z, 0.f); v.w = fmaxf(v.w, 0.f);
      hs4[i >> 2][i & 3] = v;
    }
  }
  const int v4 = tile * 64 + l;
  const bool valid = (v4 < V4);
  const int v4c = valid ? v4 : V4 - 1;   // per-lane clamp (src addr is per-lane)
  const float4* W4 = reinterpret_cast<const float4*>(W);
  float4 acc[4];
#pragma unroll
  for (int i = 0; i < 4; ++i) acc[i] = make_float4(0.f, 0.f, 0.f, 0.f);

  for (int c = 0; c < 16; ++c) {
    __syncthreads();   // prev chunk consumed by all waves (and hs ready on c=0)
#pragma unroll
    for (int j = 0; j < 4; ++j) {
      const int kr = j * 4 + w;           // local row 0..15
      const int k = c * 16 + kr;
      stage16((const float*)(W4 + ((size_t)k * V4 + v4c)), &wbuf[kr * 256]);
    }
    __syncthreads();   // drains vmcnt -> chunk staged
#pragma unroll
    for (int kr = 0; kr < 16; ++kr) {
      const int k = c * 16 + kr;
      const float4 h = hs4[k][w];  // uniform per wave: graphs 4w..4w+3
      const float4 wv = *reinterpret_cast<const float4*>(&wbuf[kr * 256 + l * 4]);
      acc[0].x = fmaf(wv.x, h.x, acc[0].x); acc[0].y = fmaf(wv.y, h.x, acc[0].y);
      acc[0].z = fmaf(wv.z, h.x, acc[0].z); acc[0].w = fmaf(wv.w, h.x, acc[0].w);
      acc[1].x = fmaf(wv.x, h.y, acc[1].x); acc[1].y = fmaf(wv.y, h.y, acc[1].y);
      acc[1].z = fmaf(wv.z, h.y, acc[1].z); acc[1].w = fmaf(wv.w, h.y, acc[1].w);
      acc[2].x = fmaf(wv.x, h.z, acc[2].x); acc[2].y = fmaf(wv.y, h.z, acc[2].y);
      acc[2].z = fmaf(wv.z, h.z, acc[2].z); acc[2].w = fmaf(wv.w, h.z, acc[2].w);
      acc[3].x = fmaf(wv.x, h.w, acc[3].x); acc[3].y = fmaf(wv.y, h.w, acc[3].y);
      acc[3].z = fmaf(wv.z, h.w, acc[3].z); acc[3].w = fmaf(wv.w, h.w, acc[3].w);
    }
  }

  const float4 bb = reinterpret_cast<const float4*>(bias)[v4c];
  float4* o4 = reinterpret_cast<float4*>(o);
#pragma unroll
  for (int i = 0; i < 4; ++i) {
    const int g = w * 4 + i;
    float4 s = acc[i];
    s.x += bb.x; s.y += bb.y; s.z += bb.z; s.w += bb.w;
    if (valid) o4[(size_t)g * V4 + v4] = s;
    float m = valid ? fmaxf(fmaxf(s.x, s.y), fmaxf(s.z, s.w)) : -INFINITY;
#pragma unroll
    for (int off = 32; off > 0; off >>= 1) m = fmaxf(m, __shfl_xor(m, off));
    float sx = valid ? (__expf(s.x - m) + __expf(s.y - m) +
                        __expf(s.z - m) + __expf(s.w - m)) : 0.f;
#pragma unroll
    for (int off = 32; off > 0; off >>= 1) sx += __shfl_xor(sx, off);
    if (l == 0) { pmh[g * ntiles + tile] = m; psh[g * ntiles + tile] = sx; }
  }
}

// grid (FTG+FTS, NB): re-reduce tile partials to L, subtract from 1024-v slice.
__global__ __launch_bounds__(256) void k_fin(
    const float* __restrict__ pm, const float* __restrict__ ps,
    float* __restrict__ out) {
  const int b = blockIdx.y;
  int head, t;
  if ((int)blockIdx.x < FTG) { head = 0; t = blockIdx.x; }
  else { head = 1; t = blockIdx.x - FTG; }
  const int V = head ? VS : VG;
  const int ntiles = head ? NTS : NTG;
  const float* pmh = pm + (head ? NB * NTG : 0) + b * ntiles;
  const float* psh = ps + (head ? NB * NTG : 0) + b * ntiles;
  const int tid = threadIdx.x;
  const int vl = tid & 63;
  const int wid = tid >> 6;

  float m = -INFINITY, s = 0.f;
  if (tid < ntiles) { m = pmh[tid]; s = psh[tid]; }
#pragma unroll
  for (int off = 32; off > 0; off >>= 1) {
    float mo = __shfl_xor(m, off);
    float so = __shfl_xor(s, off);
    float Mn = fmaxf(m, mo);
    float sn = ((m > -INFINITY) ? s * __expf(m - Mn) : 0.f) +
               ((mo > -INFINITY) ? so * __expf(mo - Mn) : 0.f);
    m = Mn; s = sn;
  }
  __shared__ float lm[4], ls[4];
  __shared__ float Lsh;
  if (vl == 0) { lm[wid] = m; ls[wid] = s; }
  __syncthreads();
  if (tid == 0) {
    float M = -INFINITY, S = 0.f;
#pragma unroll
    for (int wv = 0; wv < 4; ++wv) {
      float mi = lm[wv], si = ls[wv];
      float Mn = fmaxf(M, mi);
      S = ((M > -INFINITY) ? S * __expf(M - Mn) : 0.f) +
          ((mi > -INFINITY) ? si * __expf(mi - Mn) : 0.f);
      M = Mn;
    }
    Lsh = M + logf(S);
  }
  __syncthreads();
  const float L = Lsh;
  float* o = out + (head ? (size_t)NB * VG : 0) + (size_t)b * V;
  const int v4 = t * 256 + tid;
  if (v4 * 4 < V) {
    float4* o4 = reinterpret_cast<float4*>(o);
    float4 xv = o4[v4];
    xv.x -= L; xv.y -= L; xv.z -= L; xv.w -= L;
    o4[v4] = xv;
  }
}

extern "C" void kernel_launch(void* const* d_in, const int* in_sizes, int n_in,
                              void* d_out, int out_size, void* d_ws, size_t ws_size,
                              hipStream_t stream) {
  const float* x     = (const float*)d_in[0];
  const float* W_all = (const float*)d_in[1];
  const float* Wg    = (const float*)d_in[2];
  const float* bg    = (const float*)d_in[3];
  const float* Ws    = (const float*)d_in[4];
  const float* bs    = (const float*)d_in[5];
  const int*   ei    = (const int*)d_in[6];
  const int*   etp   = (const int*)d_in[7];
  float* out = (float*)d_out;
  float* ws  = (float*)d_ws;

  int*   mcnt    = (int*)(ws + WS_MCNT);
  int*   matches = (int*)(ws + WS_MAT);
  float* h0p     = ws + WS_H0P;
  float* pm      = ws + WS_PM;
  float* ps      = ws + WS_PS;

  dim3 gscan(NB, NCHK);
  k_scan<<<gscan, 256, 0, stream>>>(ei, etp, mcnt, matches);
  dim3 guh0(NR + 1, 8);
  k_uh0<<<guh0, 256, 0, stream>>>(x, W_all, mcnt, matches, h0p);
  k_logits<<<NTG + NTS, 256, 0, stream>>>(Wg, bg, Ws, bs, h0p, out, pm, ps);
  dim3 gfin(FTG + FTS, NB);
  k_fin<<<gfin, 256, 0, stream>>>(pm, ps, out);
}